// Round 1
// baseline (2079.569 us; speedup 1.0000x reference)
//
#include <hip/hip_runtime.h>
#include <hip/hip_bf16.h>
#include <stdint.h>

#define BB 16
#define NN 4096
#define NPOINT 1024
#define NSAMPLE 32

typedef unsigned int u32;
typedef unsigned long long u64;
typedef unsigned short u16;

__device__ inline u16 f2bf(float x){ u32 u = __float_as_uint(x); u32 r = (u + 0x7fffu + ((u>>16)&1u)) >> 16; return (u16)r; }
__device__ inline float bf2f(u32 hbits){ return __uint_as_float(hbits<<16); }

// ---------------- FPS: one block per batch, bit-exact np semantics ----------------
__global__ __launch_bounds__(256) void fps_kernel(const float* __restrict__ xyz, int* __restrict__ cents)
{
    __shared__ float lxyz[NN*3];
    __shared__ float s_bv[4]; __shared__ int s_bi[4]; __shared__ int s_far;
    const int tid = threadIdx.x;
    const int b = blockIdx.x;
    const float* gx = xyz + (size_t)b*NN*3;
    for (int i = tid; i < NN*3; i += 256) lxyz[i] = gx[i];
    if (tid == 0) s_far = 0;
    __syncthreads();
    float px[16], py[16], pz[16], dist[16];
#pragma unroll
    for (int j = 0; j < 16; j++){
        int p = tid + (j<<8);
        px[j] = lxyz[p*3+0]; py[j] = lxyz[p*3+1]; pz[j] = lxyz[p*3+2];
        dist[j] = 1e10f;
    }
    const int wid = tid >> 6, lane = tid & 63;
    for (int s = 0; s < NPOINT; s++){
        int far = s_far;
        float cx = lxyz[far*3+0], cy = lxyz[far*3+1], cz = lxyz[far*3+2];
        if (tid == 0) cents[b*NPOINT + s] = far;
        float bv = -1.0f; int bi = 0x7fffffff;
#pragma unroll
        for (int j = 0; j < 16; j++){
            float dx = __fsub_rn(px[j], cx);
            float dy = __fsub_rn(py[j], cy);
            float dz = __fsub_rn(pz[j], cz);
            float d = __fadd_rn(__fadd_rn(__fmul_rn(dx,dx), __fmul_rn(dy,dy)), __fmul_rn(dz,dz));
            float nd = fminf(dist[j], d);
            dist[j] = nd;
            if (nd > bv){ bv = nd; bi = tid + (j<<8); }  // j ascending => first-max kept
        }
#pragma unroll
        for (int off = 32; off; off >>= 1){
            float ov = __shfl_down(bv, off);
            int   oi = __shfl_down(bi, off);
            if (ov > bv || (ov == bv && oi < bi)){ bv = ov; bi = oi; }
        }
        if (lane == 0){ s_bv[wid] = bv; s_bi[wid] = bi; }
        __syncthreads();
        if (tid == 0){
            float fv = s_bv[0]; int fi = s_bi[0];
#pragma unroll
            for (int w = 1; w < 4; w++){
                float v = s_bv[w]; int i2 = s_bi[w];
                if (v > fv || (v == fv && i2 < fi)){ fv = v; fi = i2; }
            }
            s_far = fi;
        }
        __syncthreads();
    }
}

// ---------------- gather new_xyz -> d_out[0:49152] and ws copy ----------------
__global__ __launch_bounds__(256) void gather_newxyz_kernel(const float* __restrict__ xyz, const int* __restrict__ cents,
                                                            float* __restrict__ out, float* __restrict__ nxyz)
{
    int i = blockIdx.x*256 + threadIdx.x;   // < 49152
    int b = i / 3072;
    int r = i - b*3072;
    int s = r / 3;
    int c = r - s*3;
    int idx = cents[b*NPOINT + s];
    float v = xyz[((size_t)b*NN + idx)*3 + c];
    out[i] = v;
    nxyz[i] = v;
}

// ---------------- ball query: one wave per centroid, early exit ----------------
__global__ __launch_bounds__(256) void ballquery_kernel(const float* __restrict__ xyz, const float* __restrict__ nxyz,
                                                        const int* __restrict__ cents, int* __restrict__ gidx)
{
    const int lane = threadIdx.x & 63;
    const int w = (blockIdx.x << 2) + (threadIdx.x >> 6);
    const int b = w >> 10;
    const float RAD2 = (float)(0.9*0.9);
    const float* c3 = nxyz + (size_t)w*3;
    float cx = c3[0], cy = c3[1], cz = c3[2];
    float sc = __fadd_rn(__fadd_rn(__fmul_rn(cx,cx), __fmul_rn(cy,cy)), __fmul_rn(cz,cz));
    const float* gx = xyz + (size_t)b*NN*3;
    int* gout = gidx + (size_t)w*NSAMPLE;
    int found = 0; int first = -1;
    for (int base = 0; base < NN; base += 64){
        int i = base + lane;
        float pxv = gx[i*3+0], pyv = gx[i*3+1], pzv = gx[i*3+2];
        float sp = __fadd_rn(__fadd_rn(__fmul_rn(pxv,pxv), __fmul_rn(pyv,pyv)), __fmul_rn(pzv,pzv));
        float dot = __fadd_rn(__fadd_rn(__fmul_rn(cx,pxv), __fmul_rn(cy,pyv)), __fmul_rn(cz,pzv));
        float d2 = __fsub_rn(__fadd_rn(sc, sp), __fmul_rn(2.0f, dot));
        float dd = __fsqrt_rn(fmaxf(d2, 0.0f));
        bool in = !(dd > RAD2);
        u64 m = __ballot(in);
        int cnt = __popcll(m);
        if (in){
            int slot = found + __popcll(m & ((1ull<<lane) - 1ull));
            if (slot < NSAMPLE) gout[slot] = i;
        }
        if (found == 0 && cnt > 0) first = base + (__ffsll(m) - 1);
        found += cnt;
        if (found >= NSAMPLE) break;
    }
    if (found < NSAMPLE){
        if (found == 0) first = cents[w];   // unreachable safeguard (centroid is in its own ball)
        for (int slot = found + lane; slot < NSAMPLE; slot += 64) gout[slot] = first;
    }
}

// ---------------- conv1: gather 67-ch features, 67->64, +bias, store bf16 ----------------
__global__ __launch_bounds__(256) void conv1_kernel(const float* __restrict__ xyz, const float* __restrict__ points,
                                                    const float* __restrict__ nxyz, const int* __restrict__ gidx,
                                                    const float* __restrict__ w, const float* __restrict__ bias,
                                                    u32* __restrict__ xout)
{
    __shared__ float wl[67*64];   // [c][o]
    __shared__ float bl[64];
    const int tid = threadIdx.x;
    for (int i = tid; i < 67*64; i += 256){ int o = i/67, c = i - o*67; wl[c*64+o] = w[i]; }
    if (tid < 64) bl[tid] = bias[tid];
    __syncthreads();
    const int m = blockIdx.x*256 + tid;
    const int b = m >> 15;
    const int s = (m >> 5) & 1023;
    const int g = gidx[m];
    float acc[64];
#pragma unroll
    for (int o = 0; o < 64; o++) acc[o] = bl[o];
    const float* p3 = xyz + ((size_t)b*NN + g)*3;
    const float* c3 = nxyz + ((size_t)b*NPOINT + s)*3;
#pragma unroll
    for (int c = 0; c < 3; c++){
        float f = p3[c] - c3[c];
        const float* wp = &wl[c*64];
#pragma unroll
        for (int o = 0; o < 64; o++) acc[o] = fmaf(wp[o], f, acc[o]);
    }
    const float4* prow = (const float4*)(points + ((size_t)b*NN + g)*64);
#pragma unroll 1
    for (int c4 = 0; c4 < 16; c4++){
        float4 f4 = prow[c4];
        const float* wp = &wl[(3 + c4*4)*64];
#pragma unroll
        for (int o = 0; o < 64; o++){
            float a0 = fmaf(wp[o],      f4.x, acc[o]);
            a0       = fmaf(wp[64+o],   f4.y, a0);
            a0       = fmaf(wp[128+o],  f4.z, a0);
            acc[o]   = fmaf(wp[192+o],  f4.w, a0);
        }
    }
    u32* orow = xout + (size_t)m*32;
#pragma unroll
    for (int o = 0; o < 32; o++)
        orow[o] = (u32)f2bf(acc[2*o]) | ((u32)f2bf(acc[2*o+1]) << 16);
}

// ---------------- conv2: normalize+relu on load, 64->64 ----------------
__global__ __launch_bounds__(256) void conv2_kernel(const u32* __restrict__ xin, const float* __restrict__ aff,
                                                    const float* __restrict__ w, const float* __restrict__ bias,
                                                    u32* __restrict__ xout)
{
    __shared__ float wl[64*64];   // [c][o]
    __shared__ float al[64], bl[64], biasl[64];
    const int tid = threadIdx.x;
    for (int i = tid; i < 4096; i += 256){ int o = i >> 6, c = i & 63; wl[c*64+o] = w[i]; }
    if (tid < 64){ al[tid] = aff[tid]; bl[tid] = aff[128+tid]; biasl[tid] = bias[tid]; }
    __syncthreads();
    const int m = blockIdx.x*256 + tid;
    const uint4* row = (const uint4*)(xin + (size_t)m*32);
    float acc[64];
#pragma unroll
    for (int o = 0; o < 64; o++) acc[o] = biasl[o];
#pragma unroll 1
    for (int cu = 0; cu < 8; cu++){
        uint4 u = row[cu];
        u32 uu[4] = {u.x, u.y, u.z, u.w};
#pragma unroll
        for (int q = 0; q < 4; q++){
            int c = cu*8 + q*2;
            float f0 = fmaxf(fmaf(al[c],   bf2f(uu[q] & 0xffffu), bl[c]),   0.0f);
            float f1 = fmaxf(fmaf(al[c+1], bf2f(uu[q] >> 16),     bl[c+1]), 0.0f);
            const float* wp = &wl[c*64];
#pragma unroll
            for (int o = 0; o < 64; o++){
                acc[o] = fmaf(wp[o],    f0, acc[o]);
                acc[o] = fmaf(wp[64+o], f1, acc[o]);
            }
        }
    }
    u32* orow = xout + (size_t)m*32;
#pragma unroll
    for (int o = 0; o < 32; o++)
        orow[o] = (u32)f2bf(acc[2*o]) | ((u32)f2bf(acc[2*o+1]) << 16);
}

// ---------------- conv3: normalize+relu on load, 64->128 (2 threads/sample) ----------------
__global__ __launch_bounds__(256) void conv3_kernel(const u32* __restrict__ xin, const float* __restrict__ aff,
                                                    const float* __restrict__ w, const float* __restrict__ bias,
                                                    u32* __restrict__ xout)
{
    __shared__ float wl[64*128];  // [c][o]
    __shared__ float al[64], bl[64], biasl[128];
    const int tid = threadIdx.x;
    for (int i = tid; i < 8192; i += 256){ int o = i >> 6, c = i & 63; wl[c*128+o] = w[i]; }
    if (tid < 64){ al[tid] = aff[tid]; bl[tid] = aff[128+tid]; }
    if (tid < 128) biasl[tid] = bias[tid];
    __syncthreads();
    const int m = blockIdx.x*128 + (tid >> 1);
    const int h = (tid & 1) << 6;
    const uint4* row = (const uint4*)(xin + (size_t)m*32);
    float acc[64];
#pragma unroll
    for (int o = 0; o < 64; o++) acc[o] = biasl[h+o];
#pragma unroll 1
    for (int cu = 0; cu < 8; cu++){
        uint4 u = row[cu];
        u32 uu[4] = {u.x, u.y, u.z, u.w};
#pragma unroll
        for (int q = 0; q < 4; q++){
            int c = cu*8 + q*2;
            float f0 = fmaxf(fmaf(al[c],   bf2f(uu[q] & 0xffffu), bl[c]),   0.0f);
            float f1 = fmaxf(fmaf(al[c+1], bf2f(uu[q] >> 16),     bl[c+1]), 0.0f);
            const float* wp = &wl[c*128 + h];
#pragma unroll
            for (int o = 0; o < 64; o++){
                acc[o] = fmaf(wp[o],     f0, acc[o]);
                acc[o] = fmaf(wp[128+o], f1, acc[o]);
            }
        }
    }
    u32* orow = xout + (size_t)m*64 + (h >> 1);
#pragma unroll
    for (int o = 0; o < 32; o++)
        orow[o] = (u32)f2bf(acc[2*o]) | ((u32)f2bf(acc[2*o+1]) << 16);
}

// ---------------- per-channel sum/sumsq over bf16 buffer ----------------
__global__ __launch_bounds__(256) void stats_kernel(const u32* __restrict__ xin, int n_u, int C, float* __restrict__ stats)
{
    __shared__ float ls[128], lq[128];
    const int tid = threadIdx.x;
    if (tid < C){ ls[tid] = 0.0f; lq[tid] = 0.0f; }
    __syncthreads();
    int flat = blockIdx.x*256 + tid;
    const int stride = gridDim.x*256;     // divisible by C/2 => channel pair fixed per thread
    const int c0 = (2*flat) % C;
    float s0 = 0, q0 = 0, s1 = 0, q1 = 0;
    for (int i = flat; i < n_u; i += stride){
        u32 u = xin[i];
        float x0 = bf2f(u & 0xffffu);
        float x1 = bf2f(u >> 16);
        s0 += x0; q0 = fmaf(x0, x0, q0);
        s1 += x1; q1 = fmaf(x1, x1, q1);
    }
    atomicAdd(&ls[c0], s0);   atomicAdd(&lq[c0], q0);
    atomicAdd(&ls[c0+1], s1); atomicAdd(&lq[c0+1], q1);
    __syncthreads();
    if (tid < C){ atomicAdd(&stats[tid], ls[tid]); atomicAdd(&stats[128+tid], lq[tid]); }
}

__global__ void finalize_kernel(const float* __restrict__ stats, const float* __restrict__ g,
                                const float* __restrict__ beta, float* __restrict__ aff, int C)
{
    int c = threadIdx.x;
    if (c < C){
        const float invM = 1.0f / 524288.0f;
        float mu  = stats[c] * invM;
        float var = fmaxf(stats[128+c] * invM - mu*mu, 0.0f);
        float inv = 1.0f / sqrtf(var + 1e-5f);
        float a = g[c] * inv;
        aff[c] = a;
        aff[128+c] = beta[c] - mu*a;
    }
}

// ---------------- BN3 + relu + max over K, transpose to (B,S,128) ----------------
__global__ __launch_bounds__(128) void maxpool_kernel(const u16* __restrict__ x3, const float* __restrict__ aff,
                                                      float* __restrict__ out)
{
    const int bs = blockIdx.x;      // b*1024+s
    const int o = threadIdx.x;
    float a = aff[o], bsh = aff[128+o];
    const u16* base = x3 + (size_t)bs*NSAMPLE*128 + o;
    float mx = -1e30f, mn = 1e30f;
#pragma unroll 4
    for (int k = 0; k < NSAMPLE; k++){
        float v = bf2f((u32)base[k*128]);
        mx = fmaxf(mx, v); mn = fminf(mn, v);
    }
    float z = (a >= 0.0f) ? fmaf(a, mx, bsh) : fmaf(a, mn, bsh);
    out[(size_t)BB*NPOINT*3 + (size_t)bs*128 + o] = fmaxf(z, 0.0f);
}

extern "C" void kernel_launch(void* const* d_in, const int* in_sizes, int n_in,
                              void* d_out, int out_size, void* d_ws, size_t ws_size,
                              hipStream_t stream)
{
    const float* xyz    = (const float*)d_in[0];
    const float* points = (const float*)d_in[1];
    const float* w0  = (const float*)d_in[2];
    const float* b0  = (const float*)d_in[3];
    const float* g0  = (const float*)d_in[4];
    const float* be0 = (const float*)d_in[5];
    const float* w1  = (const float*)d_in[6];
    const float* b1  = (const float*)d_in[7];
    const float* g1  = (const float*)d_in[8];
    const float* be1 = (const float*)d_in[9];
    const float* w2  = (const float*)d_in[10];
    const float* b2  = (const float*)d_in[11];
    const float* g2  = (const float*)d_in[12];
    const float* be2 = (const float*)d_in[13];
    float* out = (float*)d_out;
    char* ws = (char*)d_ws;

    int*   cents = (int*)(ws + 0);                 //   64 KiB
    float* nxyz  = (float*)(ws + 65536);           //  192 KiB
    int*   gidx  = (int*)(ws + 262144);            //    2 MiB
    float* stats = (float*)(ws + 2359296);         //  3 KiB (3 layers x [sum128|sumsq128])
    float* aff   = (float*)(ws + 2362368);         //  3 KiB (3 layers x [a128|b128])
    u32* x2buf = (u32*)(ws + 2365440);             //   64 MiB  (conv2 out)
    u32* x1buf = (u32*)(ws + 2365440 + 67108864);  //   64 MiB  (conv1 out)
    u32* x3buf = x1buf;                            //  128 MiB  (conv3 out, overwrites dead x1)

    hipMemsetAsync(stats, 0, 3*256*sizeof(float), stream);
    fps_kernel<<<16, 256, 0, stream>>>(xyz, cents);
    gather_newxyz_kernel<<<192, 256, 0, stream>>>(xyz, cents, out, nxyz);
    ballquery_kernel<<<4096, 256, 0, stream>>>(xyz, nxyz, cents, gidx);
    conv1_kernel<<<2048, 256, 0, stream>>>(xyz, points, nxyz, gidx, w0, b0, x1buf);
    stats_kernel<<<256, 256, 0, stream>>>(x1buf, 16777216, 64, stats);
    finalize_kernel<<<1, 128, 0, stream>>>(stats, g0, be0, aff, 64);
    conv2_kernel<<<2048, 256, 0, stream>>>(x1buf, aff, w1, b1, x2buf);
    stats_kernel<<<256, 256, 0, stream>>>(x2buf, 16777216, 64, stats + 256);
    finalize_kernel<<<1, 128, 0, stream>>>(stats + 256, g1, be1, aff + 256, 64);
    conv3_kernel<<<4096, 256, 0, stream>>>(x2buf, aff + 256, w2, b2, x3buf);
    stats_kernel<<<256, 256, 0, stream>>>(x3buf, 33554432, 128, stats + 512);
    finalize_kernel<<<1, 128, 0, stream>>>(stats + 512, g2, be2, aff + 512, 128);
    maxpool_kernel<<<16384, 128, 0, stream>>>((const u16*)x3buf, aff + 512, out);
}

// Round 2
// 1509.349 us; speedup vs baseline: 1.3778x; 1.3778x over previous
//
#include <hip/hip_runtime.h>
#include <hip/hip_bf16.h>
#include <stdint.h>

#define BB 16
#define NN 4096
#define NPOINT 1024
#define NSAMPLE 32

typedef unsigned int u32;
typedef unsigned long long u64;
typedef unsigned short u16;

__device__ inline u16 f2bf(float x){ u32 u = __float_as_uint(x); u32 r = (u + 0x7fffu + ((u>>16)&1u)) >> 16; return (u16)r; }
__device__ inline float bf2f(u32 hbits){ return __uint_as_float(hbits<<16); }
__device__ inline u64 umax64(u64 a, u64 b){ return a > b ? a : b; }

// ---------------- FPS: 8 waves, packed-u64 argmax, ONE barrier per step ----------------
__global__ __launch_bounds__(512) void fps_kernel(const float* __restrict__ xyz, int* __restrict__ cents)
{
    __shared__ float lxyz[NN*3];
    __shared__ u64 s_red[2][8];
    const int tid = threadIdx.x;
    const int b = blockIdx.x;
    const float* gx = xyz + (size_t)b*NN*3;
    for (int i = tid; i < NN*3; i += 512) lxyz[i] = gx[i];
    __syncthreads();
    float px[8], py[8], pz[8], dist[8];
#pragma unroll
    for (int j = 0; j < 8; j++){
        int p = tid + (j<<9);
        px[j] = lxyz[p*3+0]; py[j] = lxyz[p*3+1]; pz[j] = lxyz[p*3+2];
        dist[j] = 1e10f;
    }
    int far = 0, par = 0;
    for (int s = 0; s < NPOINT; s++){
        if (tid == 0) cents[b*NPOINT + s] = far;
        float cx = lxyz[far*3+0], cy = lxyz[far*3+1], cz = lxyz[far*3+2];
        u64 pk[8];
#pragma unroll
        for (int j = 0; j < 8; j++){
            float dx = __fsub_rn(px[j], cx);
            float dy = __fsub_rn(py[j], cy);
            float dz = __fsub_rn(pz[j], cz);
            float d = __fadd_rn(__fadd_rn(__fmul_rn(dx,dx), __fmul_rn(dy,dy)), __fmul_rn(dz,dz));
            float nd = fminf(dist[j], d);
            dist[j] = nd;
            pk[j] = ((u64)__float_as_uint(nd) << 32) | (u32)(4095 - (tid + (j<<9)));
        }
        // local tree argmax (tie -> lower index via 4095-idx packing)
        u64 a0 = umax64(pk[0], pk[1]);
        u64 a1 = umax64(pk[2], pk[3]);
        u64 a2 = umax64(pk[4], pk[5]);
        u64 a3 = umax64(pk[6], pk[7]);
        u64 best = umax64(umax64(a0, a1), umax64(a2, a3));
        // wave butterfly
#pragma unroll
        for (int off = 1; off <= 32; off <<= 1){
            u64 o = __shfl_xor(best, off);
            best = umax64(best, o);
        }
        if ((tid & 63) == 0) s_red[par][tid >> 6] = best;
        __syncthreads();
        u64 r0 = umax64(s_red[par][0], s_red[par][1]);
        u64 r1 = umax64(s_red[par][2], s_red[par][3]);
        u64 r2 = umax64(s_red[par][4], s_red[par][5]);
        u64 r3 = umax64(s_red[par][6], s_red[par][7]);
        u64 m  = umax64(umax64(r0, r1), umax64(r2, r3));
        far = 4095 - (int)(m & 0xFFFFFFFFu);
        par ^= 1;
    }
}

// ---------------- gather new_xyz -> d_out[0:49152] and ws copy ----------------
__global__ __launch_bounds__(256) void gather_newxyz_kernel(const float* __restrict__ xyz, const int* __restrict__ cents,
                                                            float* __restrict__ out, float* __restrict__ nxyz)
{
    int i = blockIdx.x*256 + threadIdx.x;   // < 49152
    int b = i / 3072;
    int r = i - b*3072;
    int s = r / 3;
    int c = r - s*3;
    int idx = cents[b*NPOINT + s];
    float v = xyz[((size_t)b*NN + idx)*3 + c];
    out[i] = v;
    nxyz[i] = v;
}

// ---------------- ball query: one wave per centroid, early exit ----------------
__global__ __launch_bounds__(256) void ballquery_kernel(const float* __restrict__ xyz, const float* __restrict__ nxyz,
                                                        const int* __restrict__ cents, int* __restrict__ gidx)
{
    const int lane = threadIdx.x & 63;
    const int w = (blockIdx.x << 2) + (threadIdx.x >> 6);
    const int b = w >> 10;
    const float RAD2 = (float)(0.9*0.9);
    const float* c3 = nxyz + (size_t)w*3;
    float cx = c3[0], cy = c3[1], cz = c3[2];
    float sc = __fadd_rn(__fadd_rn(__fmul_rn(cx,cx), __fmul_rn(cy,cy)), __fmul_rn(cz,cz));
    const float* gx = xyz + (size_t)b*NN*3;
    int* gout = gidx + (size_t)w*NSAMPLE;
    int found = 0; int first = -1;
    for (int base = 0; base < NN; base += 64){
        int i = base + lane;
        float pxv = gx[i*3+0], pyv = gx[i*3+1], pzv = gx[i*3+2];
        float sp = __fadd_rn(__fadd_rn(__fmul_rn(pxv,pxv), __fmul_rn(pyv,pyv)), __fmul_rn(pzv,pzv));
        float dot = __fadd_rn(__fadd_rn(__fmul_rn(cx,pxv), __fmul_rn(cy,pyv)), __fmul_rn(cz,pzv));
        float d2 = __fsub_rn(__fadd_rn(sc, sp), __fmul_rn(2.0f, dot));
        float dd = __fsqrt_rn(fmaxf(d2, 0.0f));
        bool in = !(dd > RAD2);
        u64 m = __ballot(in);
        int cnt = __popcll(m);
        if (in){
            int slot = found + __popcll(m & ((1ull<<lane) - 1ull));
            if (slot < NSAMPLE) gout[slot] = i;
        }
        if (found == 0 && cnt > 0) first = base + (__ffsll(m) - 1);
        found += cnt;
        if (found >= NSAMPLE) break;
    }
    if (found < NSAMPLE){
        if (found == 0) first = cents[w];
        for (int slot = found + lane; slot < NSAMPLE; slot += 64) gout[slot] = first;
    }
}

// ---------------- conv1: 67->64, thread = 4 samples x 16 outputs, fused stats ----------------
__global__ __launch_bounds__(256) void conv1_kernel(const float* __restrict__ xyz, const float* __restrict__ points,
                                                    const float* __restrict__ nxyz, const int* __restrict__ gidx,
                                                    const float* __restrict__ w, const float* __restrict__ bias,
                                                    u32* __restrict__ xout, float* __restrict__ stats)
{
    __shared__ float wl[67*64];   // [c][o]
    __shared__ float bl[64], ls[64], lq[64];
    const int tid = threadIdx.x;
    for (int i = tid; i < 67*64; i += 256){ int o = i/67, c = i - o*67; wl[c*64+o] = w[i]; }
    if (tid < 64){ bl[tid] = bias[tid]; ls[tid] = 0.f; lq[tid] = 0.f; }
    __syncthreads();
    const int og = tid & 3;
    const int ob = og*16;
    const int q  = tid >> 2;
    const int m0 = blockIdx.x*256 + q*4;
    const int b = m0 >> 15;
    const int s = (m0 >> 5) & 1023;
    int g[4];
#pragma unroll
    for (int i = 0; i < 4; i++) g[i] = gidx[m0+i];
    const float* c3 = nxyz + ((size_t)b*NPOINT + s)*3;
    float cx = c3[0], cy = c3[1], cz = c3[2];
    float acc[4][16];
#pragma unroll
    for (int i = 0; i < 4; i++)
#pragma unroll
        for (int o = 0; o < 16; o++) acc[i][o] = bl[ob+o];
#pragma unroll
    for (int i = 0; i < 4; i++){
        const float* p3 = xyz + ((size_t)b*NN + g[i])*3;
        float f0 = p3[0]-cx, f1 = p3[1]-cy, f2 = p3[2]-cz;
#pragma unroll
        for (int o = 0; o < 16; o++){
            float a = acc[i][o];
            a = fmaf(wl[0*64+ob+o], f0, a);
            a = fmaf(wl[1*64+ob+o], f1, a);
            a = fmaf(wl[2*64+ob+o], f2, a);
            acc[i][o] = a;
        }
    }
    const float4* pr[4];
#pragma unroll
    for (int i = 0; i < 4; i++) pr[i] = (const float4*)(points + ((size_t)b*NN + g[i])*64);
#pragma unroll 4
    for (int c4 = 0; c4 < 16; c4++){
        float4 f[4];
#pragma unroll
        for (int i = 0; i < 4; i++) f[i] = pr[i][c4];
        const int cb = 3 + c4*4;
#pragma unroll
        for (int o = 0; o < 16; o++){
            float w0 = wl[(cb+0)*64+ob+o];
            float w1 = wl[(cb+1)*64+ob+o];
            float w2 = wl[(cb+2)*64+ob+o];
            float w3 = wl[(cb+3)*64+ob+o];
#pragma unroll
            for (int i = 0; i < 4; i++){
                float a = acc[i][o];
                a = fmaf(w0, f[i].x, a);
                a = fmaf(w1, f[i].y, a);
                a = fmaf(w2, f[i].z, a);
                acc[i][o] = fmaf(w3, f[i].w, a);
            }
        }
    }
#pragma unroll
    for (int i = 0; i < 4; i++){
        u32* orow = xout + (size_t)(m0+i)*32 + og*8;
#pragma unroll
        for (int oo = 0; oo < 8; oo++)
            orow[oo] = (u32)f2bf(acc[i][2*oo]) | ((u32)f2bf(acc[i][2*oo+1]) << 16);
    }
#pragma unroll
    for (int o = 0; o < 16; o++){
        float sv = acc[0][o]+acc[1][o]+acc[2][o]+acc[3][o];
        float qv = acc[0][o]*acc[0][o]+acc[1][o]*acc[1][o]+acc[2][o]*acc[2][o]+acc[3][o]*acc[3][o];
        atomicAdd(&ls[ob+o], sv);
        atomicAdd(&lq[ob+o], qv);
    }
    __syncthreads();
    if (tid < 64){
        float* st = stats + (blockIdx.x & 7)*256;
        atomicAdd(&st[tid], ls[tid]);
        atomicAdd(&st[128+tid], lq[tid]);
    }
}

// ---------------- conv2: 64->64, normalize+relu on load, fused stats ----------------
__global__ __launch_bounds__(256) void conv2_kernel(const u32* __restrict__ xin, const float* __restrict__ aff,
                                                    const float* __restrict__ w, const float* __restrict__ bias,
                                                    u32* __restrict__ xout, float* __restrict__ stats)
{
    __shared__ float wl[64*64];   // [c][o]
    __shared__ float al[64], blv[64], biasl[64], ls[64], lq[64];
    const int tid = threadIdx.x;
    for (int i = tid; i < 4096; i += 256){ int o = i >> 6, c = i & 63; wl[c*64+o] = w[i]; }
    if (tid < 64){ al[tid]=aff[tid]; blv[tid]=aff[128+tid]; biasl[tid]=bias[tid]; ls[tid]=0.f; lq[tid]=0.f; }
    __syncthreads();
    const int og = tid & 3;
    const int ob = og*16;
    const int q  = tid >> 2;
    const int m0 = blockIdx.x*256 + q*4;
    const uint4* r0 = (const uint4*)(xin + (size_t)m0*32);
    const uint4* r1 = r0 + 8;
    const uint4* r2 = r0 + 16;
    const uint4* r3 = r0 + 24;
    float acc[4][16];
#pragma unroll
    for (int i = 0; i < 4; i++)
#pragma unroll
        for (int o = 0; o < 16; o++) acc[i][o] = biasl[ob+o];
#pragma unroll 2
    for (int cu = 0; cu < 8; cu++){
        uint4 u0 = r0[cu], u1 = r1[cu], u2 = r2[cu], u3 = r3[cu];
        u32 wa[4][4] = {{u0.x,u0.y,u0.z,u0.w},{u1.x,u1.y,u1.z,u1.w},{u2.x,u2.y,u2.z,u2.w},{u3.x,u3.y,u3.z,u3.w}};
#pragma unroll
        for (int wd = 0; wd < 4; wd++){
            const int c = cu*8 + wd*2;
            float f0[4], f1[4];
#pragma unroll
            for (int i = 0; i < 4; i++){
                u32 uw = wa[i][wd];
                f0[i] = fmaxf(fmaf(al[c],   bf2f(uw & 0xffffu), blv[c]),   0.f);
                f1[i] = fmaxf(fmaf(al[c+1], bf2f(uw >> 16),     blv[c+1]), 0.f);
            }
#pragma unroll
            for (int o = 0; o < 16; o++){
                float w0 = wl[c*64+ob+o];
                float w1 = wl[(c+1)*64+ob+o];
#pragma unroll
                for (int i = 0; i < 4; i++){
                    float a = acc[i][o];
                    a = fmaf(w0, f0[i], a);
                    acc[i][o] = fmaf(w1, f1[i], a);
                }
            }
        }
    }
#pragma unroll
    for (int i = 0; i < 4; i++){
        u32* orow = xout + (size_t)(m0+i)*32 + og*8;
#pragma unroll
        for (int oo = 0; oo < 8; oo++)
            orow[oo] = (u32)f2bf(acc[i][2*oo]) | ((u32)f2bf(acc[i][2*oo+1]) << 16);
    }
#pragma unroll
    for (int o = 0; o < 16; o++){
        float sv = acc[0][o]+acc[1][o]+acc[2][o]+acc[3][o];
        float qv = acc[0][o]*acc[0][o]+acc[1][o]*acc[1][o]+acc[2][o]*acc[2][o]+acc[3][o]*acc[3][o];
        atomicAdd(&ls[ob+o], sv);
        atomicAdd(&lq[ob+o], qv);
    }
    __syncthreads();
    if (tid < 64){
        float* st = stats + (blockIdx.x & 7)*256;
        atomicAdd(&st[tid], ls[tid]);
        atomicAdd(&st[128+tid], lq[tid]);
    }
}

// ---------------- conv3: 64->128, fused stats + fused group max/min (no x3 write) ----------------
__global__ __launch_bounds__(256) void conv3_kernel(const u32* __restrict__ xin, const float* __restrict__ aff,
                                                    const float* __restrict__ w, const float* __restrict__ bias,
                                                    float* __restrict__ gmax, float* __restrict__ gmin,
                                                    float* __restrict__ stats)
{
    __shared__ float wl[64*128];  // [c][o]
    __shared__ float al[64], blv[64], biasl[128], ls[128], lq[128];
    const int tid = threadIdx.x;
    for (int i = tid; i < 8192; i += 256){ int o = i >> 6, c = i & 63; wl[c*128+o] = w[i]; }
    if (tid < 64){ al[tid]=aff[tid]; blv[tid]=aff[128+tid]; }
    if (tid < 128){ biasl[tid]=bias[tid]; ls[tid]=0.f; lq[tid]=0.f; }
    __syncthreads();
    const int og = tid & 7;          // 8 o-groups x 16 = 128 outputs
    const int ob = og*16;
    const int q  = tid >> 3;         // 32 quads -> 128 samples -> 4 groups per block
    const int m0 = blockIdx.x*128 + q*4;
    const uint4* r0 = (const uint4*)(xin + (size_t)m0*32);
    const uint4* r1 = r0 + 8;
    const uint4* r2 = r0 + 16;
    const uint4* r3 = r0 + 24;
    float acc[4][16];
#pragma unroll
    for (int i = 0; i < 4; i++)
#pragma unroll
        for (int o = 0; o < 16; o++) acc[i][o] = biasl[ob+o];
#pragma unroll 2
    for (int cu = 0; cu < 8; cu++){
        uint4 u0 = r0[cu], u1 = r1[cu], u2 = r2[cu], u3 = r3[cu];
        u32 wa[4][4] = {{u0.x,u0.y,u0.z,u0.w},{u1.x,u1.y,u1.z,u1.w},{u2.x,u2.y,u2.z,u2.w},{u3.x,u3.y,u3.z,u3.w}};
#pragma unroll
        for (int wd = 0; wd < 4; wd++){
            const int c = cu*8 + wd*2;
            float f0[4], f1[4];
#pragma unroll
            for (int i = 0; i < 4; i++){
                u32 uw = wa[i][wd];
                f0[i] = fmaxf(fmaf(al[c],   bf2f(uw & 0xffffu), blv[c]),   0.f);
                f1[i] = fmaxf(fmaf(al[c+1], bf2f(uw >> 16),     blv[c+1]), 0.f);
            }
#pragma unroll
            for (int o = 0; o < 16; o++){
                float w0 = wl[c*128+ob+o];
                float w1 = wl[(c+1)*128+ob+o];
#pragma unroll
                for (int i = 0; i < 4; i++){
                    float a = acc[i][o];
                    a = fmaf(w0, f0[i], a);
                    acc[i][o] = fmaf(w1, f1[i], a);
                }
            }
        }
    }
    // stats (raw conv output incl. bias)
#pragma unroll
    for (int o = 0; o < 16; o++){
        float sv = acc[0][o]+acc[1][o]+acc[2][o]+acc[3][o];
        float qv = acc[0][o]*acc[0][o]+acc[1][o]*acc[1][o]+acc[2][o]*acc[2][o]+acc[3][o]*acc[3][o];
        atomicAdd(&ls[ob+o], sv);
        atomicAdd(&lq[ob+o], qv);
    }
    // group max/min: one group per wave; quads r=q&7 are lane-groups of 8 -> shfl_xor 8/16/32
    float mx[16], mn[16];
#pragma unroll
    for (int o = 0; o < 16; o++){
        float a = fmaxf(fmaxf(acc[0][o], acc[1][o]), fmaxf(acc[2][o], acc[3][o]));
        float n = fminf(fminf(acc[0][o], acc[1][o]), fminf(acc[2][o], acc[3][o]));
        mx[o] = a; mn[o] = n;
    }
#pragma unroll
    for (int off = 8; off <= 32; off <<= 1){
#pragma unroll
        for (int o = 0; o < 16; o++){
            mx[o] = fmaxf(mx[o], __shfl_xor(mx[o], off));
            mn[o] = fminf(mn[o], __shfl_xor(mn[o], off));
        }
    }
    if ((q & 7) == 0){
        const int gq = blockIdx.x*4 + (q >> 3);
        float* gm = gmax + (size_t)gq*128 + ob;
        float* gn = gmin + (size_t)gq*128 + ob;
#pragma unroll
        for (int o = 0; o < 16; o++){ gm[o] = mx[o]; gn[o] = mn[o]; }
    }
    __syncthreads();
    if (tid < 128){
        float* st = stats + (blockIdx.x & 7)*256;
        atomicAdd(&st[tid], ls[tid]);
        atomicAdd(&st[128+tid], lq[tid]);
    }
}

// ---------------- finalize: stats (8 replicas) -> affine a,b ----------------
__global__ void finalize_kernel(const float* __restrict__ stats, const float* __restrict__ g,
                                const float* __restrict__ beta, float* __restrict__ aff, int C)
{
    int c = threadIdx.x;
    if (c < C){
        float sm = 0.f, sq = 0.f;
#pragma unroll
        for (int r = 0; r < 8; r++){ sm += stats[r*256+c]; sq += stats[r*256+128+c]; }
        const float invM = 1.0f / 524288.0f;
        float mu  = sm * invM;
        float var = fmaxf(sq * invM - mu*mu, 0.0f);
        float inv = 1.0f / sqrtf(var + 1e-5f);
        float a = g[c] * inv;
        aff[c] = a;
        aff[128+c] = beta[c] - mu*a;
    }
}

// ---------------- pool: BN3 affine + relu from group max/min ----------------
__global__ __launch_bounds__(256) void pool_kernel(const float* __restrict__ gmax, const float* __restrict__ gmin,
                                                   const float* __restrict__ aff, float* __restrict__ out)
{
    int idx = blockIdx.x*256 + threadIdx.x;   // < 2097152
    int o = idx & 127;
    float a = aff[o], bsh = aff[128+o];
    float v = (a >= 0.f) ? fmaf(a, gmax[idx], bsh) : fmaf(a, gmin[idx], bsh);
    out[(size_t)BB*NPOINT*3 + idx] = fmaxf(v, 0.f);
}

extern "C" void kernel_launch(void* const* d_in, const int* in_sizes, int n_in,
                              void* d_out, int out_size, void* d_ws, size_t ws_size,
                              hipStream_t stream)
{
    const float* xyz    = (const float*)d_in[0];
    const float* points = (const float*)d_in[1];
    const float* w0  = (const float*)d_in[2];
    const float* b0  = (const float*)d_in[3];
    const float* g0  = (const float*)d_in[4];
    const float* be0 = (const float*)d_in[5];
    const float* w1  = (const float*)d_in[6];
    const float* b1  = (const float*)d_in[7];
    const float* g1  = (const float*)d_in[8];
    const float* be1 = (const float*)d_in[9];
    const float* w2  = (const float*)d_in[10];
    const float* b2  = (const float*)d_in[11];
    const float* g2  = (const float*)d_in[12];
    const float* be2 = (const float*)d_in[13];
    float* out = (float*)d_out;
    char* ws = (char*)d_ws;

    int*   cents = (int*)(ws + 0);                 //  64 KiB
    float* nxyz  = (float*)(ws + 65536);           // 192 KiB
    int*   gidx  = (int*)(ws + 262144);            //   2 MiB -> ends 2359296
    float* stats = (float*)(ws + 2359296);         //  24 KiB (3 layers x 8 replicas x 256 f)
    float* aff   = (float*)(ws + 2383872);         //   3 KiB (3 layers x [a128|b128])
    u32*   x1buf = (u32*)(ws + 2386944);           //  64 MiB (conv1 out bf16)
    u32*   x2buf = (u32*)(ws + 69495808);          //  64 MiB (conv2 out bf16)
    float* gmax  = (float*)(ws + 136604672);       // 8.4 MiB
    float* gmin  = (float*)(ws + 144993280);       // 8.4 MiB -> ends ~153.4 MiB

    hipMemsetAsync(stats, 0, 6144*sizeof(float), stream);
    fps_kernel<<<16, 512, 0, stream>>>(xyz, cents);
    gather_newxyz_kernel<<<192, 256, 0, stream>>>(xyz, cents, out, nxyz);
    ballquery_kernel<<<4096, 256, 0, stream>>>(xyz, nxyz, cents, gidx);
    conv1_kernel<<<2048, 256, 0, stream>>>(xyz, points, nxyz, gidx, w0, b0, x1buf, stats);
    finalize_kernel<<<1, 128, 0, stream>>>(stats, g0, be0, aff, 64);
    conv2_kernel<<<2048, 256, 0, stream>>>(x1buf, aff, w1, b1, x2buf, stats + 2048);
    finalize_kernel<<<1, 128, 0, stream>>>(stats + 2048, g1, be1, aff + 256, 64);
    conv3_kernel<<<4096, 256, 0, stream>>>(x2buf, aff + 256, w2, b2, gmax, gmin, stats + 4096);
    finalize_kernel<<<1, 128, 0, stream>>>(stats + 4096, g2, be2, aff + 512, 128);
    pool_kernel<<<8192, 256, 0, stream>>>(gmax, gmin, aff + 512, out);
}

// Round 3
// 1261.952 us; speedup vs baseline: 1.6479x; 1.1960x over previous
//
#include <hip/hip_runtime.h>
#include <hip/hip_bf16.h>
#include <stdint.h>

#define BB 16
#define NN 4096
#define NPOINT 1024
#define NSAMPLE 32

typedef unsigned int u32;
typedef unsigned long long u64;
typedef unsigned short u16;
typedef float f32x2 __attribute__((ext_vector_type(2)));

__device__ inline u16 f2bf(float x){ u32 u = __float_as_uint(x); u32 r = (u + 0x7fffu + ((u>>16)&1u)) >> 16; return (u16)r; }
__device__ inline float bf2f(u32 hbits){ return __uint_as_float(hbits<<16); }
__device__ inline u64 umax64(u64 a, u64 b){ return a > b ? a : b; }

// full-wave (64-lane) f32 max via DPP; result bits returned from lane 63.
__device__ inline int wave_max_bits(float v){
    int x = __float_as_int(v);
    int t;
    t = __builtin_amdgcn_update_dpp(0, x, 0x111, 0xf, 0xf, true);  // row_shr:1
    x = __float_as_int(fmaxf(__int_as_float(x), __int_as_float(t)));
    t = __builtin_amdgcn_update_dpp(0, x, 0x112, 0xf, 0xf, true);  // row_shr:2
    x = __float_as_int(fmaxf(__int_as_float(x), __int_as_float(t)));
    t = __builtin_amdgcn_update_dpp(0, x, 0x114, 0xf, 0xf, true);  // row_shr:4
    x = __float_as_int(fmaxf(__int_as_float(x), __int_as_float(t)));
    t = __builtin_amdgcn_update_dpp(0, x, 0x118, 0xf, 0xf, true);  // row_shr:8
    x = __float_as_int(fmaxf(__int_as_float(x), __int_as_float(t)));
    t = __builtin_amdgcn_update_dpp(0, x, 0x142, 0xf, 0xf, true);  // row_bcast:15
    x = __float_as_int(fmaxf(__int_as_float(x), __int_as_float(t)));
    t = __builtin_amdgcn_update_dpp(0, x, 0x143, 0xf, 0xf, true);  // row_bcast:31
    x = __float_as_int(fmaxf(__int_as_float(x), __int_as_float(t)));
    return __builtin_amdgcn_readlane(x, 63);
}

// ---------------- FPS: 4 waves, DPP value-max + scalar index recovery ----------------
__global__ __launch_bounds__(256) void fps_kernel(const float* __restrict__ xyz, int* __restrict__ cents)
{
#pragma clang fp contract(off)
    __shared__ float lxyz[NN*3];
    __shared__ __align__(16) u64 s_red[2][4];
    const int tid = threadIdx.x;
    const int b = blockIdx.x;
    const float* gx = xyz + (size_t)b*NN*3;
    for (int i = tid; i < NN*3; i += 256) lxyz[i] = gx[i];
    __syncthreads();
    // chunked: thread owns points p = tid*16 + j, j in [0,16), stored as 8 float2 pairs
    f32x2 px[8], py[8], pz[8], dist[8];
#pragma unroll
    for (int jj = 0; jj < 8; jj++){
        int p = tid*16 + jj*2;
        px[jj] = (f32x2){ lxyz[p*3+0], lxyz[(p+1)*3+0] };
        py[jj] = (f32x2){ lxyz[p*3+1], lxyz[(p+1)*3+1] };
        pz[jj] = (f32x2){ lxyz[p*3+2], lxyz[(p+1)*3+2] };
        dist[jj] = (f32x2){ 1e10f, 1e10f };
    }
    const int lane = tid & 63;
    const int wid = tid >> 6;
    int far = 0, par = 0;
    for (int s = 0; s < NPOINT; s++){
        if (tid == 0) cents[b*NPOINT + s] = far;
        float cx = lxyz[far*3+0], cy = lxyz[far*3+1], cz = lxyz[far*3+2];
        f32x2 c2x = { cx, cx }, c2y = { cy, cy }, c2z = { cz, cz };
        float bv = -1.0f; int bj = 0;
#pragma unroll
        for (int jj = 0; jj < 8; jj++){
            f32x2 dx = px[jj] - c2x;
            f32x2 dy = py[jj] - c2y;
            f32x2 dz = pz[jj] - c2z;
            f32x2 d  = (dx*dx + dy*dy) + dz*dz;     // contract(off): exact _rn order
            f32x2 nd;
            nd.x = fminf(dist[jj].x, d.x);
            nd.y = fminf(dist[jj].y, d.y);
            dist[jj] = nd;
            if (nd.x > bv){ bv = nd.x; bj = jj*2; }       // ascending j => first-max kept
            if (nd.y > bv){ bv = nd.y; bj = jj*2+1; }
        }
        int wmb = wave_max_bits(bv);
        float wmax = __int_as_float(wmb);
        u64 mask = __ballot(bv == wmax);
        int fl = __ffsll(mask) - 1;                       // lowest lane => lowest p chunk
        int fj = __builtin_amdgcn_readlane(bj, fl);
        int p = (wid<<10) + (fl<<4) + fj;
        if (lane == 0) s_red[par][wid] = ((u64)(u32)wmb << 32) | (u32)(4095 - p);
        __syncthreads();
        u64 m0 = umax64(s_red[par][0], s_red[par][1]);
        u64 m1 = umax64(s_red[par][2], s_red[par][3]);
        u64 m  = umax64(m0, m1);
        far = 4095 - (int)(m & 0xFFFu);
        par ^= 1;
    }
}

// ---------------- gather new_xyz -> d_out[0:49152] and ws copy ----------------
__global__ __launch_bounds__(256) void gather_newxyz_kernel(const float* __restrict__ xyz, const int* __restrict__ cents,
                                                            float* __restrict__ out, float* __restrict__ nxyz)
{
    int i = blockIdx.x*256 + threadIdx.x;   // < 49152
    int b = i / 3072;
    int r = i - b*3072;
    int s = r / 3;
    int c = r - s*3;
    int idx = cents[b*NPOINT + s];
    float v = xyz[((size_t)b*NN + idx)*3 + c];
    out[i] = v;
    nxyz[i] = v;
}

// ---------------- ball query: one wave per centroid, early exit ----------------
__global__ __launch_bounds__(256) void ballquery_kernel(const float* __restrict__ xyz, const float* __restrict__ nxyz,
                                                        const int* __restrict__ cents, int* __restrict__ gidx)
{
    const int lane = threadIdx.x & 63;
    const int w = (blockIdx.x << 2) + (threadIdx.x >> 6);
    const int b = w >> 10;
    const float RAD2 = (float)(0.9*0.9);
    const float* c3 = nxyz + (size_t)w*3;
    float cx = c3[0], cy = c3[1], cz = c3[2];
    float sc = __fadd_rn(__fadd_rn(__fmul_rn(cx,cx), __fmul_rn(cy,cy)), __fmul_rn(cz,cz));
    const float* gx = xyz + (size_t)b*NN*3;
    int* gout = gidx + (size_t)w*NSAMPLE;
    int found = 0; int first = -1;
    for (int base = 0; base < NN; base += 64){
        int i = base + lane;
        float pxv = gx[i*3+0], pyv = gx[i*3+1], pzv = gx[i*3+2];
        float sp = __fadd_rn(__fadd_rn(__fmul_rn(pxv,pxv), __fmul_rn(pyv,pyv)), __fmul_rn(pzv,pzv));
        float dot = __fadd_rn(__fadd_rn(__fmul_rn(cx,pxv), __fmul_rn(cy,pyv)), __fmul_rn(cz,pzv));
        float d2 = __fsub_rn(__fadd_rn(sc, sp), __fmul_rn(2.0f, dot));
        float dd = __fsqrt_rn(fmaxf(d2, 0.0f));
        bool in = !(dd > RAD2);
        u64 m = __ballot(in);
        int cnt = __popcll(m);
        if (in){
            int slot = found + __popcll(m & ((1ull<<lane) - 1ull));
            if (slot < NSAMPLE) gout[slot] = i;
        }
        if (found == 0 && cnt > 0) first = base + (__ffsll(m) - 1);
        found += cnt;
        if (found >= NSAMPLE) break;
    }
    if (found < NSAMPLE){
        if (found == 0) first = cents[w];
        for (int slot = found + lane; slot < NSAMPLE; slot += 64) gout[slot] = first;
    }
}

// ---------------- conv1: 67->64, thread = 4 samples x 16 outputs, fused stats ----------------
__global__ __launch_bounds__(256) void conv1_kernel(const float* __restrict__ xyz, const float* __restrict__ points,
                                                    const float* __restrict__ nxyz, const int* __restrict__ gidx,
                                                    const float* __restrict__ w, const float* __restrict__ bias,
                                                    u32* __restrict__ xout, float* __restrict__ stats)
{
    __shared__ float wl[67*64];   // [c][o]
    __shared__ float bl[64], ls[64], lq[64];
    const int tid = threadIdx.x;
    for (int i = tid; i < 67*64; i += 256){ int o = i/67, c = i - o*67; wl[c*64+o] = w[i]; }
    if (tid < 64){ bl[tid] = bias[tid]; ls[tid] = 0.f; lq[tid] = 0.f; }
    __syncthreads();
    const int og = tid & 3;
    const int ob = og*16;
    const int q  = tid >> 2;
    const int m0 = blockIdx.x*256 + q*4;
    const int b = m0 >> 15;
    const int s = (m0 >> 5) & 1023;
    int g[4];
#pragma unroll
    for (int i = 0; i < 4; i++) g[i] = gidx[m0+i];
    const float* c3 = nxyz + ((size_t)b*NPOINT + s)*3;
    float cx = c3[0], cy = c3[1], cz = c3[2];
    float acc[4][16];
    {
        float bv[16];
#pragma unroll
        for (int t4 = 0; t4 < 4; t4++) ((float4*)bv)[t4] = *(const float4*)&bl[ob + t4*4];
#pragma unroll
        for (int i = 0; i < 4; i++)
#pragma unroll
            for (int o = 0; o < 16; o++) acc[i][o] = bv[o];
    }
    float fx[4], fy[4], fz[4];
#pragma unroll
    for (int i = 0; i < 4; i++){
        const float* p3 = xyz + ((size_t)b*NN + g[i])*3;
        fx[i] = p3[0]-cx; fy[i] = p3[1]-cy; fz[i] = p3[2]-cz;
    }
#pragma unroll
    for (int c = 0; c < 3; c++){
        float wv[16];
#pragma unroll
        for (int t4 = 0; t4 < 4; t4++) ((float4*)wv)[t4] = *(const float4*)&wl[c*64 + ob + t4*4];
        const float* f = (c == 0) ? fx : (c == 1) ? fy : fz;
#pragma unroll
        for (int o = 0; o < 16; o++)
#pragma unroll
            for (int i = 0; i < 4; i++) acc[i][o] = fmaf(wv[o], f[i], acc[i][o]);
    }
    const float4* pr[4];
#pragma unroll
    for (int i = 0; i < 4; i++) pr[i] = (const float4*)(points + ((size_t)b*NN + g[i])*64);
#pragma unroll 4
    for (int c4 = 0; c4 < 16; c4++){
        float4 f[4];
#pragma unroll
        for (int i = 0; i < 4; i++) f[i] = pr[i][c4];
        const int cb = 3 + c4*4;
#pragma unroll
        for (int k = 0; k < 4; k++){
            float wv[16];
#pragma unroll
            for (int t4 = 0; t4 < 4; t4++) ((float4*)wv)[t4] = *(const float4*)&wl[(cb+k)*64 + ob + t4*4];
#pragma unroll
            for (int o = 0; o < 16; o++){
                float wk = wv[o];
#pragma unroll
                for (int i = 0; i < 4; i++){
                    const float* fp = (const float*)&f[i];
                    acc[i][o] = fmaf(wk, fp[k], acc[i][o]);
                }
            }
        }
    }
#pragma unroll
    for (int i = 0; i < 4; i++){
        u32* orow = xout + (size_t)(m0+i)*32 + og*8;
#pragma unroll
        for (int oo = 0; oo < 8; oo++)
            orow[oo] = (u32)f2bf(acc[i][2*oo]) | ((u32)f2bf(acc[i][2*oo+1]) << 16);
    }
#pragma unroll
    for (int o = 0; o < 16; o++){
        float sv = acc[0][o]+acc[1][o]+acc[2][o]+acc[3][o];
        float qv = acc[0][o]*acc[0][o]+acc[1][o]*acc[1][o]+acc[2][o]*acc[2][o]+acc[3][o]*acc[3][o];
        atomicAdd(&ls[ob+o], sv);
        atomicAdd(&lq[ob+o], qv);
    }
    __syncthreads();
    if (tid < 64){
        float* st = stats + (blockIdx.x & 7)*256;
        atomicAdd(&st[tid], ls[tid]);
        atomicAdd(&st[128+tid], lq[tid]);
    }
}

// ---------------- conv2: 64->64, normalize+relu on load, fused stats ----------------
__global__ __launch_bounds__(256) void conv2_kernel(const u32* __restrict__ xin, const float* __restrict__ aff,
                                                    const float* __restrict__ w, const float* __restrict__ bias,
                                                    u32* __restrict__ xout, float* __restrict__ stats)
{
    __shared__ float wl[64*64];   // [c][o]
    __shared__ float al[64], blv[64], biasl[64], ls[64], lq[64];
    const int tid = threadIdx.x;
    for (int i = tid; i < 4096; i += 256){ int o = i >> 6, c = i & 63; wl[c*64+o] = w[i]; }
    if (tid < 64){ al[tid]=aff[tid]; blv[tid]=aff[128+tid]; biasl[tid]=bias[tid]; ls[tid]=0.f; lq[tid]=0.f; }
    __syncthreads();
    const int og = tid & 3;
    const int ob = og*16;
    const int q  = tid >> 2;
    const int m0 = blockIdx.x*256 + q*4;
    const uint4* r0 = (const uint4*)(xin + (size_t)m0*32);
    const uint4* r1 = r0 + 8;
    const uint4* r2 = r0 + 16;
    const uint4* r3 = r0 + 24;
    float acc[4][16];
    {
        float bv[16];
#pragma unroll
        for (int t4 = 0; t4 < 4; t4++) ((float4*)bv)[t4] = *(const float4*)&biasl[ob + t4*4];
#pragma unroll
        for (int i = 0; i < 4; i++)
#pragma unroll
            for (int o = 0; o < 16; o++) acc[i][o] = bv[o];
    }
#pragma unroll 2
    for (int cu = 0; cu < 8; cu++){
        uint4 u0 = r0[cu], u1 = r1[cu], u2 = r2[cu], u3 = r3[cu];
        u32 wa[4][4] = {{u0.x,u0.y,u0.z,u0.w},{u1.x,u1.y,u1.z,u1.w},{u2.x,u2.y,u2.z,u2.w},{u3.x,u3.y,u3.z,u3.w}};
#pragma unroll
        for (int wd = 0; wd < 4; wd++){
            const int c = cu*8 + wd*2;
            float f0[4], f1[4];
#pragma unroll
            for (int i = 0; i < 4; i++){
                u32 uw = wa[i][wd];
                f0[i] = fmaxf(fmaf(al[c],   bf2f(uw & 0xffffu), blv[c]),   0.f);
                f1[i] = fmaxf(fmaf(al[c+1], bf2f(uw >> 16),     blv[c+1]), 0.f);
            }
            float w0v[16], w1v[16];
#pragma unroll
            for (int t4 = 0; t4 < 4; t4++){
                ((float4*)w0v)[t4] = *(const float4*)&wl[c*64     + ob + t4*4];
                ((float4*)w1v)[t4] = *(const float4*)&wl[(c+1)*64 + ob + t4*4];
            }
#pragma unroll
            for (int o = 0; o < 16; o++){
                float w0 = w0v[o], w1 = w1v[o];
#pragma unroll
                for (int i = 0; i < 4; i++){
                    float a = acc[i][o];
                    a = fmaf(w0, f0[i], a);
                    acc[i][o] = fmaf(w1, f1[i], a);
                }
            }
        }
    }
#pragma unroll
    for (int i = 0; i < 4; i++){
        u32* orow = xout + (size_t)(m0+i)*32 + og*8;
#pragma unroll
        for (int oo = 0; oo < 8; oo++)
            orow[oo] = (u32)f2bf(acc[i][2*oo]) | ((u32)f2bf(acc[i][2*oo+1]) << 16);
    }
#pragma unroll
    for (int o = 0; o < 16; o++){
        float sv = acc[0][o]+acc[1][o]+acc[2][o]+acc[3][o];
        float qv = acc[0][o]*acc[0][o]+acc[1][o]*acc[1][o]+acc[2][o]*acc[2][o]+acc[3][o]*acc[3][o];
        atomicAdd(&ls[ob+o], sv);
        atomicAdd(&lq[ob+o], qv);
    }
    __syncthreads();
    if (tid < 64){
        float* st = stats + (blockIdx.x & 7)*256;
        atomicAdd(&st[tid], ls[tid]);
        atomicAdd(&st[128+tid], lq[tid]);
    }
}

// ---------------- conv3: 64->128, fused stats + fused group max/min (no x3 write) ----------------
__global__ __launch_bounds__(256) void conv3_kernel(const u32* __restrict__ xin, const float* __restrict__ aff,
                                                    const float* __restrict__ w, const float* __restrict__ bias,
                                                    float* __restrict__ gmax, float* __restrict__ gmin,
                                                    float* __restrict__ stats)
{
    __shared__ float wl[64*128];  // [c][o]
    __shared__ float al[64], blv[64], biasl[128], ls[128], lq[128];
    const int tid = threadIdx.x;
    for (int i = tid; i < 8192; i += 256){ int o = i >> 6, c = i & 63; wl[c*128+o] = w[i]; }
    if (tid < 64){ al[tid]=aff[tid]; blv[tid]=aff[128+tid]; }
    if (tid < 128){ biasl[tid]=bias[tid]; ls[tid]=0.f; lq[tid]=0.f; }
    __syncthreads();
    const int og = tid & 7;          // 8 o-groups x 16 = 128 outputs
    const int ob = og*16;
    const int q  = tid >> 3;         // 32 quads -> 128 samples -> 4 groups per block
    const int m0 = blockIdx.x*128 + q*4;
    const uint4* r0 = (const uint4*)(xin + (size_t)m0*32);
    const uint4* r1 = r0 + 8;
    const uint4* r2 = r0 + 16;
    const uint4* r3 = r0 + 24;
    float acc[4][16];
    {
        float bv[16];
#pragma unroll
        for (int t4 = 0; t4 < 4; t4++) ((float4*)bv)[t4] = *(const float4*)&biasl[ob + t4*4];
#pragma unroll
        for (int i = 0; i < 4; i++)
#pragma unroll
            for (int o = 0; o < 16; o++) acc[i][o] = bv[o];
    }
#pragma unroll 2
    for (int cu = 0; cu < 8; cu++){
        uint4 u0 = r0[cu], u1 = r1[cu], u2 = r2[cu], u3 = r3[cu];
        u32 wa[4][4] = {{u0.x,u0.y,u0.z,u0.w},{u1.x,u1.y,u1.z,u1.w},{u2.x,u2.y,u2.z,u2.w},{u3.x,u3.y,u3.z,u3.w}};
#pragma unroll
        for (int wd = 0; wd < 4; wd++){
            const int c = cu*8 + wd*2;
            float f0[4], f1[4];
#pragma unroll
            for (int i = 0; i < 4; i++){
                u32 uw = wa[i][wd];
                f0[i] = fmaxf(fmaf(al[c],   bf2f(uw & 0xffffu), blv[c]),   0.f);
                f1[i] = fmaxf(fmaf(al[c+1], bf2f(uw >> 16),     blv[c+1]), 0.f);
            }
            float w0v[16], w1v[16];
#pragma unroll
            for (int t4 = 0; t4 < 4; t4++){
                ((float4*)w0v)[t4] = *(const float4*)&wl[c*128     + ob + t4*4];
                ((float4*)w1v)[t4] = *(const float4*)&wl[(c+1)*128 + ob + t4*4];
            }
#pragma unroll
            for (int o = 0; o < 16; o++){
                float w0 = w0v[o], w1 = w1v[o];
#pragma unroll
                for (int i = 0; i < 4; i++){
                    float a = acc[i][o];
                    a = fmaf(w0, f0[i], a);
                    acc[i][o] = fmaf(w1, f1[i], a);
                }
            }
        }
    }
    // stats (raw conv output incl. bias)
#pragma unroll
    for (int o = 0; o < 16; o++){
        float sv = acc[0][o]+acc[1][o]+acc[2][o]+acc[3][o];
        float qv = acc[0][o]*acc[0][o]+acc[1][o]*acc[1][o]+acc[2][o]*acc[2][o]+acc[3][o]*acc[3][o];
        atomicAdd(&ls[ob+o], sv);
        atomicAdd(&lq[ob+o], qv);
    }
    // group max/min: one group per wave; quads are lane-groups of 8 -> shfl_xor 8/16/32
    float mx[16], mn[16];
#pragma unroll
    for (int o = 0; o < 16; o++){
        float a = fmaxf(fmaxf(acc[0][o], acc[1][o]), fmaxf(acc[2][o], acc[3][o]));
        float n = fminf(fminf(acc[0][o], acc[1][o]), fminf(acc[2][o], acc[3][o]));
        mx[o] = a; mn[o] = n;
    }
#pragma unroll
    for (int off = 8; off <= 32; off <<= 1){
#pragma unroll
        for (int o = 0; o < 16; o++){
            mx[o] = fmaxf(mx[o], __shfl_xor(mx[o], off));
            mn[o] = fminf(mn[o], __shfl_xor(mn[o], off));
        }
    }
    if ((q & 7) == 0){
        const int gq = blockIdx.x*4 + (q >> 3);
        float* gm = gmax + (size_t)gq*128 + ob;
        float* gn = gmin + (size_t)gq*128 + ob;
#pragma unroll
        for (int o = 0; o < 16; o++){ gm[o] = mx[o]; gn[o] = mn[o]; }
    }
    __syncthreads();
    if (tid < 128){
        float* st = stats + (blockIdx.x & 7)*256;
        atomicAdd(&st[tid], ls[tid]);
        atomicAdd(&st[128+tid], lq[tid]);
    }
}

// ---------------- finalize: stats (8 replicas) -> affine a,b ----------------
__global__ void finalize_kernel(const float* __restrict__ stats, const float* __restrict__ g,
                                const float* __restrict__ beta, float* __restrict__ aff, int C)
{
    int c = threadIdx.x;
    if (c < C){
        float sm = 0.f, sq = 0.f;
#pragma unroll
        for (int r = 0; r < 8; r++){ sm += stats[r*256+c]; sq += stats[r*256+128+c]; }
        const float invM = 1.0f / 524288.0f;
        float mu  = sm * invM;
        float var = fmaxf(sq * invM - mu*mu, 0.0f);
        float inv = 1.0f / sqrtf(var + 1e-5f);
        float a = g[c] * inv;
        aff[c] = a;
        aff[128+c] = beta[c] - mu*a;
    }
}

// ---------------- pool: BN3 affine + relu from group max/min ----------------
__global__ __launch_bounds__(256) void pool_kernel(const float* __restrict__ gmax, const float* __restrict__ gmin,
                                                   const float* __restrict__ aff, float* __restrict__ out)
{
    int idx = blockIdx.x*256 + threadIdx.x;   // < 2097152
    int o = idx & 127;
    float a = aff[o], bsh = aff[128+o];
    float v = (a >= 0.f) ? fmaf(a, gmax[idx], bsh) : fmaf(a, gmin[idx], bsh);
    out[(size_t)BB*NPOINT*3 + idx] = fmaxf(v, 0.f);
}

extern "C" void kernel_launch(void* const* d_in, const int* in_sizes, int n_in,
                              void* d_out, int out_size, void* d_ws, size_t ws_size,
                              hipStream_t stream)
{
    const float* xyz    = (const float*)d_in[0];
    const float* points = (const float*)d_in[1];
    const float* w0  = (const float*)d_in[2];
    const float* b0  = (const float*)d_in[3];
    const float* g0  = (const float*)d_in[4];
    const float* be0 = (const float*)d_in[5];
    const float* w1  = (const float*)d_in[6];
    const float* b1  = (const float*)d_in[7];
    const float* g1  = (const float*)d_in[8];
    const float* be1 = (const float*)d_in[9];
    const float* w2  = (const float*)d_in[10];
    const float* b2  = (const float*)d_in[11];
    const float* g2  = (const float*)d_in[12];
    const float* be2 = (const float*)d_in[13];
    float* out = (float*)d_out;
    char* ws = (char*)d_ws;

    int*   cents = (int*)(ws + 0);                 //  64 KiB
    float* nxyz  = (float*)(ws + 65536);           // 192 KiB
    int*   gidx  = (int*)(ws + 262144);            //   2 MiB -> ends 2359296
    float* stats = (float*)(ws + 2359296);         //  24 KiB (3 layers x 8 replicas x 256 f)
    float* aff   = (float*)(ws + 2383872);         //   3 KiB (3 layers x [a128|b128])
    u32*   x1buf = (u32*)(ws + 2386944);           //  64 MiB (conv1 out bf16)
    u32*   x2buf = (u32*)(ws + 69495808);          //  64 MiB (conv2 out bf16)
    float* gmax  = (float*)(ws + 136604672);       // 8.4 MiB
    float* gmin  = (float*)(ws + 144993280);       // 8.4 MiB

    hipMemsetAsync(stats, 0, 6144*sizeof(float), stream);
    fps_kernel<<<16, 256, 0, stream>>>(xyz, cents);
    gather_newxyz_kernel<<<192, 256, 0, stream>>>(xyz, cents, out, nxyz);
    ballquery_kernel<<<4096, 256, 0, stream>>>(xyz, nxyz, cents, gidx);
    conv1_kernel<<<2048, 256, 0, stream>>>(xyz, points, nxyz, gidx, w0, b0, x1buf, stats);
    finalize_kernel<<<1, 128, 0, stream>>>(stats, g0, be0, aff, 64);
    conv2_kernel<<<2048, 256, 0, stream>>>(x1buf, aff, w1, b1, x2buf, stats + 2048);
    finalize_kernel<<<1, 128, 0, stream>>>(stats + 2048, g1, be1, aff + 256, 64);
    conv3_kernel<<<4096, 256, 0, stream>>>(x2buf, aff + 256, w2, b2, gmax, gmin, stats + 4096);
    finalize_kernel<<<1, 128, 0, stream>>>(stats + 4096, g2, be2, aff + 512, 128);
    pool_kernel<<<8192, 256, 0, stream>>>(gmax, gmin, aff + 512, out);
}